// Round 5
// baseline (483.018 us; speedup 1.0000x reference)
//
#include <hip/hip_runtime.h>
#include <hip/hip_bf16.h>

// (B, nf, D, H, W) = (4, 48, 12, 56, 56), fp32 in/out, bf16 MFMA internally.
// Sampled tensors are channels-last bf16 ([loc][48], 96B/pixel). The bilinear
// footprint is STAGED into LDS per (kd,kh) with coalesced loads; B-fragments
// interpolate directly from the staged window (kills the per-lane L1 gather
// storm that bounded round 4 at ~64 line-touches per load instruction).
constexpr int B_ = 4, C_ = 48, D_ = 12, H_ = 56, W_ = 56;
constexpr int DHW_ = D_ * H_ * W_;        // 37632
constexpr int NLOC_ = B_ * DHW_;          // 150528
constexpr int OFFC_ = 54;                 // 27 taps x 2 (dh, dw)
constexpr int NXCD_ = 8;
constexpr int HB_ = 4;                    // H-rows per block (one row per wave)
constexpr int NHB_ = H_ / HB_;            // 14
constexpr int NBLK_ = B_ * D_ * NHB_;     // 672 blocks (div by 8 -> bijective swizzle)

// staged window geometry: cols -2..57, 7 chunks (16B) per pixel (6 data + 1 pad
// for bank spread -> 112B pitch)
constexpr int SCOLS_ = 60;
constexpr int CPITCH_ = 7;                         // chunks per pixel
constexpr int RPITCH_ = SCOLS_ * CPITCH_;          // 420 chunks per row

typedef short bf16x8 __attribute__((ext_vector_type(8)));
typedef float f32x4  __attribute__((ext_vector_type(4)));
typedef unsigned int u32x4 __attribute__((ext_vector_type(4)));
typedef unsigned int u32x2 __attribute__((ext_vector_type(2)));

__device__ __forceinline__ int xcd_swizzle(int bid, int nwg) {
    int xcd = bid % NXCD_, lid = bid / NXCD_;
    int q = nwg / NXCD_, r = nwg % NXCD_;
    return (xcd < r ? xcd * (q + 1) : r * (q + 1) + (xcd - r) * q) + lid;
}

__device__ __forceinline__ unsigned int f2bf_u(float f) {
    __hip_bfloat16 h = __float2bfloat16(f);
    return (unsigned int)__builtin_bit_cast(unsigned short, h);
}
__device__ __forceinline__ float bflo(unsigned int pv) {
    return __builtin_bit_cast(float, pv << 16);
}
__device__ __forceinline__ float bfhi(unsigned int pv) {
    return __builtin_bit_cast(float, pv & 0xffff0000u);
}

__device__ __forceinline__ bf16x8 interp4(u32x4 c00, u32x4 c01, u32x4 c10, u32x4 c11,
                                          f32x4 cw) {
    u32x4 pv;
#pragma unroll
    for (int u = 0; u < 4; ++u) {
        float lo = cw[0] * bflo(c00[u]);
        lo = fmaf(cw[1], bflo(c01[u]), lo);
        lo = fmaf(cw[2], bflo(c10[u]), lo);
        lo = fmaf(cw[3], bflo(c11[u]), lo);
        float hi = cw[0] * bfhi(c00[u]);
        hi = fmaf(cw[1], bfhi(c01[u]), hi);
        hi = fmaf(cw[2], bfhi(c10[u]), hi);
        hi = fmaf(cw[3], bfhi(c11[u]), hi);
        pv[u] = f2bf_u(lo) | (f2bf_u(hi) << 16);
    }
    return __builtin_bit_cast(bf16x8, pv);
}

// Stage R rows (row0..row0+R-1) x cols -2..57 of plane (pd) into LDS,
// zero-padded outside the volume. pd must be valid. Coalesced 16B chunks.
template <int R>
__device__ __forceinline__ void stage_rows(const unsigned short* __restrict__ cb, int pd,
                                           int row0, unsigned short* SG, int tid) {
    constexpr int CHUNKS = R * SCOLS_ * 6;   // data chunks only
    for (int i = tid; i < CHUNKS; i += 256) {
        int s = i / (SCOLS_ * 6);
        int rem = i - s * (SCOLS_ * 6);
        int col = rem / 6;
        int oct = rem - col * 6;
        int r = row0 + s;
        int wq = col - 2;
        u32x4 v = {0, 0, 0, 0};
        if (r >= 0 && r < H_ && wq >= 0 && wq < W_) {
            const unsigned short* p = cb + ((size_t)(pd * H_ + r) * W_ + wq) * 48 + oct * 8;
            v = *(const u32x4*)p;
        }
        *(u32x4*)(SG + (size_t)(s * RPITCH_ + col * CPITCH_ + oct) * 8) = v;
    }
}

// Pack weights into MFMA A-fragment order (bf16):
// wf[k][mt][ks][lane][i] = W[oc=mt*16+(lane&15)][c=ks*32+8*(lane>>4)+i][tap k]
__global__ void __launch_bounds__(256) repack_frag_kernel(
    const float* __restrict__ w, unsigned short* __restrict__ wf, int OC, int MT) {
    int t = blockIdx.x * 256 + threadIdx.x;
    int total = 27 * MT * 1024;
    if (t >= total) return;
    int i    = t & 7;
    int lane = (t >> 3) & 63;
    int ks   = (t >> 9) & 1;
    int mt   = (t >> 10) % MT;
    int k    = t / (MT << 10);
    int oc = mt * 16 + (lane & 15);
    int c  = ks * 32 + 8 * (lane >> 4) + i;
    float v = (oc < OC && c < 48) ? w[((size_t)oc * 48 + c) * 27 + k] : 0.0f;
    wf[t] = (unsigned short)f2bf_u(v);
}

// fp32 [B][48][DHW] -> bf16 channels-last [B*DHW][48].
__global__ void __launch_bounds__(256) to_cl_kernel(const float* __restrict__ x,
                                                    unsigned short* __restrict__ xcl) {
    int loc = blockIdx.x * 256 + threadIdx.x;
    int b = loc / DHW_, s = loc - b * DHW_;
    const float* xp = x + (size_t)b * (C_ * DHW_) + s;
    u32x4 o[6];
#pragma unroll
    for (int q = 0; q < 6; ++q) {
        float v[8];
#pragma unroll
        for (int u = 0; u < 8; ++u) v[u] = xp[(size_t)(q * 8 + u) * DHW_];
#pragma unroll
        for (int u = 0; u < 4; ++u)
            o[q][u] = f2bf_u(v[2 * u]) | (f2bf_u(v[2 * u + 1]) << 16);
    }
    u32x4* dst = (u32x4*)(xcl + (size_t)loc * 48);
#pragma unroll
    for (int q = 0; q < 6; ++q) dst[q] = o[q];
}

// ---------------- offset conv (plain 3x3x3, 54 outputs) via MFMA ----------------
__global__ void __launch_bounds__(256) offconv_mfma(
    const unsigned short* __restrict__ xcl,   // [NLOC][48] bf16 channels-last
    const unsigned short* __restrict__ wf,    // frag-packed, MT=4
    const float* __restrict__ bo,             // [54]
    float* __restrict__ off) {                // [B][54][DHW] fp32
    __shared__ unsigned short SG[4 * RPITCH_ * 8];   // 26880 B
    int tid = threadIdx.x, wid = tid >> 6, lane = tid & 63;
    int bid = xcd_swizzle(blockIdx.x, gridDim.x);
    int hb = bid % NHB_;
    int t2 = bid / NHB_;
    int dd = t2 % D_;
    int b  = t2 / D_;
    int hbase = hb * HB_;
    int h = hbase + wid;
    int g = lane >> 4, li = lane & 15;

    f32x4 acc[4][4];
#pragma unroll
    for (int mt = 0; mt < 4; ++mt)
#pragma unroll
        for (int nt = 0; nt < 4; ++nt) acc[mt][nt] = (f32x4){0.f, 0.f, 0.f, 0.f};

    const unsigned short* cb = xcl + (size_t)b * DHW_ * 48;

#pragma unroll 1
    for (int kd = -1; kd <= 1; ++kd) {
        int pd = dd + kd;
        if (pd < 0 || pd >= D_) continue;   // uniform per block
#pragma unroll 1
        for (int kh = -1; kh <= 1; ++kh) {
            __syncthreads();
            stage_rows<4>(cb, pd, hbase + kh, SG, tid);
            __syncthreads();
#pragma unroll 1
            for (int kw = -1; kw <= 1; ++kw) {
                int k = (kd + 1) * 9 + (kh + 1) * 3 + (kw + 1);
                const unsigned short* wk = wf + (size_t)k * 4096 + lane * 8;
                bf16x8 a[4][2];
#pragma unroll
                for (int mt = 0; mt < 4; ++mt)
#pragma unroll
                    for (int ks = 0; ks < 2; ++ks)
                        a[mt][ks] = *(const bf16x8*)&wk[(mt * 2 + ks) * 512];
                int rowbase = wid * RPITCH_ * 8;   // slot = wid (row h+kh)
#pragma unroll
                for (int nt = 0; nt < 4; ++nt) {
                    int col = min(nt * 16 + li, 55) + kw + 2;   // within [1,58]
                    int cbase = rowbase + col * (CPITCH_ * 8);
#pragma unroll
                    for (int ks = 0; ks < 2; ++ks) {
                        int oct = 4 * ks + g;
                        bf16x8 bf = (bf16x8){0, 0, 0, 0, 0, 0, 0, 0};
                        if (oct < 6) bf = *(const bf16x8*)&SG[cbase + oct * 8];
#pragma unroll
                        for (int mt = 0; mt < 4; ++mt)
                            acc[mt][nt] = __builtin_amdgcn_mfma_f32_16x16x32_bf16(
                                a[mt][ks], bf, acc[mt][nt], 0, 0, 0);
                    }
                }
            }
        }
    }
    int sbase = (dd * H_ + h) * W_;
#pragma unroll
    for (int mt = 0; mt < 4; ++mt) {
#pragma unroll
        for (int r = 0; r < 4; ++r) {
            int oc = mt * 16 + 4 * g + r;
            if (oc < OFFC_) {
                float bb = bo[oc];
#pragma unroll
                for (int nt = 0; nt < 4; ++nt) {
                    int col = nt * 16 + li;
                    if (col < W_)
                        off[((size_t)b * OFFC_ + oc) * DHW_ + sbase + col] =
                            acc[mt][nt][r] + bb;
                }
            }
        }
    }
}

// ---------------- deformable conv (bilinear HW, integer D) via MFMA ----------------
template <int LEAKY, int RESID, int CLOUT>
__global__ void __launch_bounds__(256) deform_mfma(
    const unsigned short* __restrict__ scl,   // [NLOC][48] bf16 channels-last
    const float* __restrict__ off,            // [B][54][DHW] fp32
    const unsigned short* __restrict__ wf,    // frag-packed, MT=3
    const float* __restrict__ bias,           // [48]
    const float* __restrict__ resid,          // [B][48][DHW] fp32 (RESID)
    float* __restrict__ dstf,                 // [B][48][DHW] fp32 (!CLOUT)
    unsigned short* __restrict__ dstcl) {     // [NLOC][48] bf16 (CLOUT)
    __shared__ unsigned short SG[6 * RPITCH_ * 8];   // 40320 B
    __shared__ unsigned short META[4 * 64 * 24];     // 48 B per loc, per wave
    int tid = threadIdx.x, wid = tid >> 6, lane = tid & 63;
    int bid = xcd_swizzle(blockIdx.x, gridDim.x);
    int hb = bid % NHB_;
    int t2 = bid / NHB_;
    int dd = t2 % D_;
    int b  = t2 / D_;
    int hbase = hb * HB_;
    int h = hbase + wid;
    int g = lane >> 4, li = lane & 15;
    int wcol = min(lane, W_ - 1);   // lanes 56..63 clone lane 55 (results unstored)

    f32x4 acc[3][4];
#pragma unroll
    for (int mt = 0; mt < 3; ++mt)
#pragma unroll
        for (int nt = 0; nt < 4; ++nt) acc[mt][nt] = (f32x4){0.f, 0.f, 0.f, 0.f};

    const unsigned short* cb = scl + (size_t)b * DHW_ * 48;
    const float* ob = off + (size_t)b * (OFFC_ * DHW_) + (dd * H_ + h) * W_ + wcol;
    unsigned short* MW = &META[wid * 64 * 24];

#pragma unroll 1
    for (int kd = -1; kd <= 1; ++kd) {
        int pd = dd + kd;
        if (pd < 0 || pd >= D_) continue;   // uniform per block: tap group = 0
#pragma unroll 1
        for (int kh = -1; kh <= 1; ++kh) {
            int row0 = hbase + kh - 1;
            __syncthreads();
            stage_rows<6>(cb, pd, row0, SG, tid);
            __syncthreads();
#pragma unroll 1
            for (int kw = -1; kw <= 1; ++kw) {
                int k = (kd + 1) * 9 + (kh + 1) * 3 + (kw + 1);
                int hkh = h + kh, wkw = wcol + kw;
                float odh = ob[(size_t)(2 * k) * DHW_];
                float odw = ob[(size_t)(2 * k + 1) * DHW_];
                float phf = (float)hkh + odh;
                float pwf = (float)wkw + odw;
                float h0f = floorf(phf), w0f = floorf(pwf);
                float th = phf - h0f, tw = pwf - w0f;
                int h0 = (int)h0f, w0 = (int)w0f;
                // corner weights with reference's validity masking (vd true here)
                bool vh0 = (h0 >= 0) & (h0 < H_),  vh1 = (h0 + 1 >= 0) & (h0 + 1 < H_);
                bool vw0 = (w0 >= 0) & (w0 < W_),  vw1 = (w0 + 1 >= 0) & (w0 + 1 < W_);
                f32x4 cw;
                cw[0] = (vh0 & vw0) ? (1.f - th) * (1.f - tw) : 0.f;
                cw[1] = (vh0 & vw1) ? (1.f - th) * tw : 0.f;
                cw[2] = (vh1 & vw0) ? th * (1.f - tw) : 0.f;
                cw[3] = (vh1 & vw1) ? th * tw : 0.f;
                bool ok = ((unsigned)(h0 - hkh + 1) <= 1u) &
                          ((unsigned)(w0 - wkw + 1) <= 1u);
                *(f32x4*)&MW[lane * 24] = cw;
                *(u32x2*)&MW[lane * 24 + 8] = (u32x2){(unsigned)h0, (unsigned)w0};
                bool fast = __all(ok);

                const unsigned short* wk = wf + (size_t)k * 3072 + lane * 8;
                bf16x8 a[3][2];
#pragma unroll
                for (int mt = 0; mt < 3; ++mt)
#pragma unroll
                    for (int ks = 0; ks < 2; ++ks)
                        a[mt][ks] = *(const bf16x8*)&wk[(mt * 2 + ks) * 512];

                if (fast) {
#pragma unroll
                    for (int nt = 0; nt < 4; ++nt) {
                        int loc = nt * 16 + li;
                        f32x4 cwv = *(const f32x4*)&MW[loc * 24];
                        u32x2 hw = *(const u32x2*)&MW[loc * 24 + 8];
                        int slot = (int)hw[0] - row0;          // in [wid, wid+1]
                        int colb = (int)hw[1] + 2;             // in [0, 57]
                        int cbase = (slot * RPITCH_ + colb * CPITCH_) * 8;
#pragma unroll
                        for (int ks = 0; ks < 2; ++ks) {
                            int oct = 4 * ks + g;
                            bf16x8 bf = (bf16x8){0, 0, 0, 0, 0, 0, 0, 0};
                            if (oct < 6) {
                                const unsigned short* p = &SG[cbase + oct * 8];
                                u32x4 c00 = *(const u32x4*)p;
                                u32x4 c01 = *(const u32x4*)(p + CPITCH_ * 8);
                                u32x4 c10 = *(const u32x4*)(p + RPITCH_ * 8);
                                u32x4 c11 = *(const u32x4*)(p + (RPITCH_ + CPITCH_) * 8);
                                bf = interp4(c00, c01, c10, c11, cwv);
                            }
#pragma unroll
                            for (int mt = 0; mt < 3; ++mt)
                                acc[mt][nt] = __builtin_amdgcn_mfma_f32_16x16x32_bf16(
                                    a[mt][ks], bf, acc[mt][nt], 0, 0, 0);
                        }
                    }
                } else {
                    // rare fallback: clamped global gathers (reference-exact)
#pragma unroll
                    for (int nt = 0; nt < 4; ++nt) {
                        int loc = nt * 16 + li;
                        f32x4 cwv = *(const f32x4*)&MW[loc * 24];
                        u32x2 hw = *(const u32x2*)&MW[loc * 24 + 8];
                        int h0l = (int)hw[0], w0l = (int)hw[1];
                        int hc0 = min(max(h0l, 0), H_ - 1), hc1 = min(max(h0l + 1, 0), H_ - 1);
                        int wc0 = min(max(w0l, 0), W_ - 1), wc1 = min(max(w0l + 1, 0), W_ - 1);
                        const unsigned short* p00 = cb + ((size_t)(pd * H_ + hc0) * W_ + wc0) * 48;
                        const unsigned short* p01 = cb + ((size_t)(pd * H_ + hc0) * W_ + wc1) * 48;
                        const unsigned short* p10 = cb + ((size_t)(pd * H_ + hc1) * W_ + wc0) * 48;
                        const unsigned short* p11 = cb + ((size_t)(pd * H_ + hc1) * W_ + wc1) * 48;
#pragma unroll
                        for (int ks = 0; ks < 2; ++ks) {
                            int oct = 4 * ks + g;
                            bf16x8 bf = (bf16x8){0, 0, 0, 0, 0, 0, 0, 0};
                            if (oct < 6) {
                                u32x4 c00 = *(const u32x4*)(p00 + oct * 8);
                                u32x4 c01 = *(const u32x4*)(p01 + oct * 8);
                                u32x4 c10 = *(const u32x4*)(p10 + oct * 8);
                                u32x4 c11 = *(const u32x4*)(p11 + oct * 8);
                                bf = interp4(c00, c01, c10, c11, cwv);
                            }
#pragma unroll
                            for (int mt = 0; mt < 3; ++mt)
                                acc[mt][nt] = __builtin_amdgcn_mfma_f32_16x16x32_bf16(
                                    a[mt][ks], bf, acc[mt][nt], 0, 0, 0);
                        }
                    }
                }
            }
        }
    }

    if (CLOUT) {
        __syncthreads();   // staging reads done everywhere before scratch reuse
        unsigned short* Sb = SG + wid * 4096;   // [64][64] u16 wave-private tile
#pragma unroll
        for (int mt = 0; mt < 3; ++mt) {
#pragma unroll
            for (int nt = 0; nt < 4; ++nt) {
                float v[4];
#pragma unroll
                for (int r = 0; r < 4; ++r) {
                    int oc = mt * 16 + 4 * g + r;
                    float t = acc[mt][nt][r] + bias[oc];
                    if (LEAKY) t = (t >= 0.f) ? t : 0.1f * t;
                    v[r] = t;
                }
                int row = nt * 16 + li;
                int colb = (mt * 32 + 8 * g) ^ ((li & 7) << 4);
                u32x2 pp = {f2bf_u(v[0]) | (f2bf_u(v[1]) << 16),
                            f2bf_u(v[2]) | (f2bf_u(v[3]) << 16)};
                *(u32x2*)((char*)(Sb + (size_t)row * 64) + colb) = pp;
            }
        }
        if (lane < W_) {
            unsigned short* myrow = Sb + (size_t)lane * 64;
            size_t locg = (size_t)((b * D_ + dd) * H_ + h) * W_ + lane;
            u32x4* dcl = (u32x4*)(dstcl + locg * 48);
#pragma unroll
            for (int s = 0; s < 6; ++s)
                dcl[s] = *(u32x4*)((char*)myrow + ((s * 16) ^ ((lane & 7) << 4)));
        }
    } else {
        int sbase = (dd * H_ + h) * W_;
#pragma unroll
        for (int mt = 0; mt < 3; ++mt) {
#pragma unroll
            for (int r = 0; r < 4; ++r) {
                int oc = mt * 16 + 4 * g + r;
                float bb = bias[oc];
#pragma unroll
                for (int nt = 0; nt < 4; ++nt) {
                    int col = nt * 16 + li;
                    if (col < W_) {
                        size_t addr = ((size_t)b * C_ + oc) * DHW_ + sbase + col;
                        float v = acc[mt][nt][r] + bb;
                        if (LEAKY) v = (v >= 0.0f) ? v : 0.1f * v;
                        if (RESID) v += resid[addr];
                        dstf[addr] = v;
                    }
                }
            }
        }
    }
}

extern "C" void kernel_launch(void* const* d_in, const int* in_sizes, int n_in,
                              void* d_out, int out_size, void* d_ws, size_t ws_size,
                              hipStream_t stream) {
    const float* x      = (const float*)d_in[0];
    const float* w_off0 = (const float*)d_in[1];
    const float* b_off0 = (const float*)d_in[2];
    const float* w0     = (const float*)d_in[3];
    const float* b0     = (const float*)d_in[4];
    const float* w_off1 = (const float*)d_in[5];
    const float* b_off1 = (const float*)d_in[6];
    const float* w1     = (const float*)d_in[7];
    const float* b1     = (const float*)d_in[8];
    float* out = (float*)d_out;

    // ws: off (54*NLOC f32) | xcl (NLOC*48 bf16) | hcl (NLOC*48 bf16) | wf_off | wf_conv
    float* off_buf = (float*)d_ws;
    unsigned short* xcl = (unsigned short*)(off_buf + (size_t)OFFC_ * NLOC_);
    unsigned short* hcl = xcl + (size_t)NLOC_ * 48;
    unsigned short* wf_off  = hcl + (size_t)NLOC_ * 48;
    unsigned short* wf_conv = wf_off + 27 * 4 * 1024;

    dim3 blk(256);

    to_cl_kernel<<<NLOC_ / 256, blk, 0, stream>>>(x, xcl);

    // --- layer 0 ---
    repack_frag_kernel<<<(27 * 4 * 1024 + 255) / 256, blk, 0, stream>>>(w_off0, wf_off, OFFC_, 4);
    repack_frag_kernel<<<(27 * 3 * 1024 + 255) / 256, blk, 0, stream>>>(w0, wf_conv, C_, 3);
    offconv_mfma<<<NBLK_, blk, 0, stream>>>(xcl, wf_off, b_off0, off_buf);
    deform_mfma<1, 0, 1><<<NBLK_, blk, 0, stream>>>(xcl, off_buf, wf_conv, b0, nullptr, nullptr, hcl);

    // --- layer 1 ---
    repack_frag_kernel<<<(27 * 4 * 1024 + 255) / 256, blk, 0, stream>>>(w_off1, wf_off, OFFC_, 4);
    repack_frag_kernel<<<(27 * 3 * 1024 + 255) / 256, blk, 0, stream>>>(w1, wf_conv, C_, 3);
    offconv_mfma<<<NBLK_, blk, 0, stream>>>(hcl, wf_off, b_off1, off_buf);
    deform_mfma<0, 1, 0><<<NBLK_, blk, 0, stream>>>(hcl, off_buf, wf_conv, b1, x, out, nullptr);
}

// Round 6
// 354.048 us; speedup vs baseline: 1.3643x; 1.3643x over previous
//
#include <hip/hip_runtime.h>
#include <hip/hip_bf16.h>

// (B, nf, D, H, W) = (4, 48, 12, 56, 56), fp32 in/out, bf16 MFMA internally.
// Sampled tensors are stored as SIX bf16 chunk-planes [6][NLOC][8ch]: each
// bilinear corner load is a 16B read at 16B pixel stride, so a wave's 64
// lanes touch ~16 cache lines per instruction instead of ~60 (the 96B/pixel
// channels-last layout that bounded round 4 at L1 line-touch throughput).
constexpr int B_ = 4, C_ = 48, D_ = 12, H_ = 56, W_ = 56;
constexpr int DHW_ = D_ * H_ * W_;        // 37632 (divisible by 256)
constexpr int NLOC_ = B_ * DHW_;          // 150528 -> 588 blocks of 256
constexpr int OFFC_ = 54;                 // 27 taps x 2 (dh, dw)
constexpr int NXCD_ = 8;

typedef short bf16x8 __attribute__((ext_vector_type(8)));
typedef float f32x4  __attribute__((ext_vector_type(4)));
typedef unsigned int u32x4 __attribute__((ext_vector_type(4)));
typedef unsigned int u32x2 __attribute__((ext_vector_type(2)));

__device__ __forceinline__ int xcd_swizzle(int bid, int nwg) {
    int xcd = bid % NXCD_, lid = bid / NXCD_;
    int q = nwg / NXCD_, r = nwg % NXCD_;
    return (xcd < r ? xcd * (q + 1) : r * (q + 1) + (xcd - r) * q) + lid;
}

__device__ __forceinline__ unsigned int f2bf_u(float f) {
    __hip_bfloat16 h = __float2bfloat16(f);
    return (unsigned int)__builtin_bit_cast(unsigned short, h);
}
__device__ __forceinline__ float bflo(unsigned int pv) {
    return __builtin_bit_cast(float, pv << 16);
}
__device__ __forceinline__ float bfhi(unsigned int pv) {
    return __builtin_bit_cast(float, pv & 0xffff0000u);
}

// 4-corner bilinear on a 16B chunk (8 bf16 channels), fp32 math, bf16 out.
__device__ __forceinline__ u32x4 interp4(u32x4 c00, u32x4 c01, u32x4 c10, u32x4 c11,
                                         f32x4 cw) {
    u32x4 pv;
#pragma unroll
    for (int u = 0; u < 4; ++u) {
        float lo = cw[0] * bflo(c00[u]);
        lo = fmaf(cw[1], bflo(c01[u]), lo);
        lo = fmaf(cw[2], bflo(c10[u]), lo);
        lo = fmaf(cw[3], bflo(c11[u]), lo);
        float hi = cw[0] * bfhi(c00[u]);
        hi = fmaf(cw[1], bfhi(c01[u]), hi);
        hi = fmaf(cw[2], bfhi(c10[u]), hi);
        hi = fmaf(cw[3], bfhi(c11[u]), hi);
        pv[u] = f2bf_u(lo) | (f2bf_u(hi) << 16);
    }
    return pv;
}

// Pack weights into MFMA A-fragment order (bf16):
// wf[k][mt][ks][lane][i] = W[oc=mt*16+(lane&15)][c=ks*32+8*(lane>>4)+i][tap k]
__global__ void __launch_bounds__(256) repack_frag_kernel(
    const float* __restrict__ w, unsigned short* __restrict__ wf, int OC, int MT) {
    int t = blockIdx.x * 256 + threadIdx.x;
    int total = 27 * MT * 1024;
    if (t >= total) return;
    int i    = t & 7;
    int lane = (t >> 3) & 63;
    int ks   = (t >> 9) & 1;
    int mt   = (t >> 10) % MT;
    int k    = t / (MT << 10);
    int oc = mt * 16 + (lane & 15);
    int c  = ks * 32 + 8 * (lane >> 4) + i;
    float v = (oc < OC && c < 48) ? w[((size_t)oc * 48 + c) * 27 + k] : 0.0f;
    wf[t] = (unsigned short)f2bf_u(v);
}

// fp32 [B][48][DHW] -> bf16 chunk-planes [6][NLOC][8].
__global__ void __launch_bounds__(256) to_cl_kernel(const float* __restrict__ x,
                                                    unsigned short* __restrict__ xcl) {
    int loc = blockIdx.x * 256 + threadIdx.x;
    int b = loc / DHW_, s = loc - b * DHW_;
    const float* xp = x + (size_t)b * (C_ * DHW_) + s;
#pragma unroll
    for (int q = 0; q < 6; ++q) {
        float v[8];
#pragma unroll
        for (int u = 0; u < 8; ++u) v[u] = xp[(size_t)(q * 8 + u) * DHW_];
        u32x4 o;
#pragma unroll
        for (int u = 0; u < 4; ++u)
            o[u] = f2bf_u(v[2 * u]) | (f2bf_u(v[2 * u + 1]) << 16);
        *(u32x4*)(xcl + ((size_t)q * NLOC_ + loc) * 8) = o;   // 16B/lane dense
    }
}

// ---------------- offset conv (plain 3x3x3, 54 outputs) via MFMA ----------------
__global__ void __launch_bounds__(256) offconv_mfma(
    const unsigned short* __restrict__ xcl,   // [6][NLOC][8] bf16 chunk-planes
    const unsigned short* __restrict__ wf,    // frag-packed, MT=4
    const float* __restrict__ bo,             // [54]
    float* __restrict__ off) {                // [B][54][DHW] fp32
    __shared__ unsigned short S[4][64][64];
    int tid = threadIdx.x, wid = tid >> 6, lane = tid & 63;
    int base = xcd_swizzle(blockIdx.x, gridDim.x) * 256 + wid * 64;
    int loc = base + lane;
    int b = loc / DHW_;
    int sp = loc - b * DHW_;
    int w = sp % W_; int t1 = sp / W_;
    int h = t1 % H_; int d = t1 / H_;
    int g = lane >> 4, li = lane & 15, l7 = lane & 7;

    u32x4 z = {0, 0, 0, 0};
    *(u32x4*)&S[wid][lane][(6 ^ l7) * 8] = z;   // K-pad channels 48..63
    *(u32x4*)&S[wid][lane][(7 ^ l7) * 8] = z;

    f32x4 acc[4][4];
#pragma unroll
    for (int mt = 0; mt < 4; ++mt)
#pragma unroll
        for (int nt = 0; nt < 4; ++nt) acc[mt][nt] = (f32x4){0.f, 0.f, 0.f, 0.f};

    const u32x4* plane[6];
#pragma unroll
    for (int q = 0; q < 6; ++q)
        plane[q] = (const u32x4*)(xcl + ((size_t)q * NLOC_ + (size_t)b * DHW_) * 8);

#pragma unroll 1
    for (int k = 0; k < 27; ++k) {
        int kd = k / 9 - 1, kh = (k / 3) % 3 - 1, kw = k % 3 - 1;
        int pd = d + kd, ph = h + kh, pw = w + kw;
        bool valid = (pd >= 0) & (pd < D_) & (ph >= 0) & (ph < H_) & (pw >= 0) & (pw < W_);
        int pdc = min(max(pd, 0), D_ - 1);
        int phc = min(max(ph, 0), H_ - 1);
        int pwc = min(max(pw, 0), W_ - 1);
        int pix = (pdc * H_ + phc) * W_ + pwc;
        u32x4 pv[6];
#pragma unroll
        for (int cc = 0; cc < 6; ++cc) pv[cc] = plane[cc][pix];   // coalesced 16B
#pragma unroll
        for (int cc = 0; cc < 6; ++cc) {
            if (!valid) pv[cc] = z;
            *(u32x4*)&S[wid][lane][(cc ^ l7) * 8] = pv[cc];
        }
        const unsigned short* wk = wf + (size_t)k * 4096 + lane * 8;
        bf16x8 a[4][2];
#pragma unroll
        for (int mt = 0; mt < 4; ++mt)
#pragma unroll
            for (int ks = 0; ks < 2; ++ks)
                a[mt][ks] = *(const bf16x8*)&wk[(mt * 2 + ks) * 512];
#pragma unroll
        for (int nt = 0; nt < 4; ++nt) {
            const unsigned short* sr = &S[wid][nt * 16 + li][0];
            bf16x8 b0 = *(const bf16x8*)&sr[((0 + g) ^ l7) * 8];
            bf16x8 b1 = *(const bf16x8*)&sr[((4 + g) ^ l7) * 8];
#pragma unroll
            for (int mt = 0; mt < 4; ++mt) {
                acc[mt][nt] = __builtin_amdgcn_mfma_f32_16x16x32_bf16(a[mt][0], b0, acc[mt][nt], 0, 0, 0);
                acc[mt][nt] = __builtin_amdgcn_mfma_f32_16x16x32_bf16(a[mt][1], b1, acc[mt][nt], 0, 0, 0);
            }
        }
    }
    int s0 = base - b * DHW_;
#pragma unroll
    for (int mt = 0; mt < 4; ++mt) {
#pragma unroll
        for (int r = 0; r < 4; ++r) {
            int oc = mt * 16 + 4 * g + r;
            if (oc < OFFC_) {
                float bb = bo[oc];
#pragma unroll
                for (int nt = 0; nt < 4; ++nt) {
                    size_t addr = ((size_t)b * OFFC_ + oc) * DHW_ + (s0 + nt * 16 + li);
                    off[addr] = acc[mt][nt][r] + bb;
                }
            }
        }
    }
}

// ---------------- deformable conv (bilinear HW, integer D) via MFMA ----------------
template <int LEAKY, int RESID, int CLOUT>
__global__ void __launch_bounds__(256) deform_mfma(
    const unsigned short* __restrict__ scl,   // [6][NLOC][8] bf16 chunk-planes
    const float* __restrict__ off,            // [B][54][DHW] fp32
    const unsigned short* __restrict__ wf,    // frag-packed, MT=3
    const float* __restrict__ bias,           // [48]
    const float* __restrict__ resid,          // [B][48][DHW] fp32 (RESID)
    float* __restrict__ dstf,                 // [B][48][DHW] fp32 (!CLOUT)
    unsigned short* __restrict__ dstcl) {     // [6][NLOC][8] bf16 (CLOUT)
    __shared__ unsigned short S[4][64][64];
    int tid = threadIdx.x, wid = tid >> 6, lane = tid & 63;
    int base = xcd_swizzle(blockIdx.x, gridDim.x) * 256 + wid * 64;
    int loc = base + lane;
    int b = loc / DHW_;
    int sp = loc - b * DHW_;
    int w = sp % W_; int t1 = sp / W_;
    int h = t1 % H_; int d = t1 / H_;
    int g = lane >> 4, li = lane & 15, l7 = lane & 7;

    u32x4 z = {0, 0, 0, 0};
    *(u32x4*)&S[wid][lane][(6 ^ l7) * 8] = z;
    *(u32x4*)&S[wid][lane][(7 ^ l7) * 8] = z;

    f32x4 acc[3][4];
#pragma unroll
    for (int mt = 0; mt < 3; ++mt)
#pragma unroll
        for (int nt = 0; nt < 4; ++nt) acc[mt][nt] = (f32x4){0.f, 0.f, 0.f, 0.f};

    const u32x4* plane[6];
#pragma unroll
    for (int q = 0; q < 6; ++q)
        plane[q] = (const u32x4*)(scl + ((size_t)q * NLOC_ + (size_t)b * DHW_) * 8);
    const float* ob = off + (size_t)b * (OFFC_ * DHW_) + sp;

#pragma unroll 1
    for (int k = 0; k < 27; ++k) {
        int kd = k / 9 - 1, kh = (k / 3) % 3 - 1, kw = k % 3 - 1;
        int pd = d + kd;
        bool vd = (pd >= 0) & (pd < D_);
        int pdc = min(max(pd, 0), D_ - 1);

        float odh = ob[(size_t)(2 * k + 0) * DHW_];
        float odw = ob[(size_t)(2 * k + 1) * DHW_];
        float phf = (float)(h + kh) + odh;
        float pwf = (float)(w + kw) + odw;
        float h0f = floorf(phf), w0f = floorf(pwf);
        float th = phf - h0f, tw = pwf - w0f;
        int h0 = (int)h0f, w0 = (int)w0f;

        int pix[4];
        f32x4 cw;
#pragma unroll
        for (int dh = 0; dh < 2; ++dh) {
            int hh = h0 + dh;
            bool vh = vd & (hh >= 0) & (hh < H_);
            int hhc = min(max(hh, 0), H_ - 1);
            float wh = dh ? th : 1.0f - th;
#pragma unroll
            for (int dw = 0; dw < 2; ++dw) {
                int ww = w0 + dw;
                bool v = vh & (ww >= 0) & (ww < W_);
                int wwc = min(max(ww, 0), W_ - 1);
                float wwt = dw ? tw : 1.0f - tw;
                pix[dh * 2 + dw] = (pdc * H_ + hhc) * W_ + wwc;   // clamped in-bounds
                cw[dh * 2 + dw] = v ? wh * wwt : 0.0f;
            }
        }

        // two halves of 12 staged 16B gathers (3 chunk-planes x 4 corners)
#pragma unroll
        for (int half = 0; half < 2; ++half) {
            u32x4 st[3][4];
#pragma unroll
            for (int cc = 0; cc < 3; ++cc)
#pragma unroll
                for (int j = 0; j < 4; ++j)
                    st[cc][j] = plane[half * 3 + cc][pix[j]];
#pragma unroll
            for (int cc = 0; cc < 3; ++cc) {
                u32x4 pv = interp4(st[cc][0], st[cc][1], st[cc][2], st[cc][3], cw);
                *(u32x4*)&S[wid][lane][((half * 3 + cc) ^ l7) * 8] = pv;
            }
        }

        const unsigned short* wk = wf + (size_t)k * 3072 + lane * 8;
        bf16x8 a[3][2];
#pragma unroll
        for (int mt = 0; mt < 3; ++mt)
#pragma unroll
            for (int ks = 0; ks < 2; ++ks)
                a[mt][ks] = *(const bf16x8*)&wk[(mt * 2 + ks) * 512];
#pragma unroll
        for (int nt = 0; nt < 4; ++nt) {
            const unsigned short* sr = &S[wid][nt * 16 + li][0];
            bf16x8 b0 = *(const bf16x8*)&sr[((0 + g) ^ l7) * 8];
            bf16x8 b1 = *(const bf16x8*)&sr[((4 + g) ^ l7) * 8];
#pragma unroll
            for (int mt = 0; mt < 3; ++mt) {
                acc[mt][nt] = __builtin_amdgcn_mfma_f32_16x16x32_bf16(a[mt][0], b0, acc[mt][nt], 0, 0, 0);
                acc[mt][nt] = __builtin_amdgcn_mfma_f32_16x16x32_bf16(a[mt][1], b1, acc[mt][nt], 0, 0, 0);
            }
        }
    }

    if (CLOUT) {
        // Transpose D-tile through the (now free) wave-private LDS tile, then
        // write bf16 chunk-planes: 16B/lane dense per plane, fully coalesced.
        unsigned short* Sb = &S[wid][0][0];   // row stride 64 u16 = 128 B
#pragma unroll
        for (int mt = 0; mt < 3; ++mt) {
#pragma unroll
            for (int nt = 0; nt < 4; ++nt) {
                float v[4];
#pragma unroll
                for (int r = 0; r < 4; ++r) {
                    int oc = mt * 16 + 4 * g + r;
                    float t = acc[mt][nt][r] + bias[oc];
                    if (LEAKY) t = (t >= 0.f) ? t : 0.1f * t;
                    v[r] = t;
                }
                int row = nt * 16 + li;
                int colb = (mt * 32 + 8 * g) ^ ((li & 7) << 4);
                u32x2 pp = {f2bf_u(v[0]) | (f2bf_u(v[1]) << 16),
                            f2bf_u(v[2]) | (f2bf_u(v[3]) << 16)};
                *(u32x2*)((char*)(Sb + (size_t)row * 64) + colb) = pp;
            }
        }
        unsigned short* myrow = Sb + (size_t)lane * 64;
#pragma unroll
        for (int s = 0; s < 6; ++s) {
            u32x4 c = *(u32x4*)((char*)myrow + ((s * 16) ^ ((lane & 7) << 4)));
            *(u32x4*)(dstcl + ((size_t)s * NLOC_ + loc) * 8) = c;
        }
    } else {
        int s0 = base - b * DHW_;
#pragma unroll
        for (int mt = 0; mt < 3; ++mt) {
#pragma unroll
            for (int r = 0; r < 4; ++r) {
                int oc = mt * 16 + 4 * g + r;
                float bb = bias[oc];
#pragma unroll
                for (int nt = 0; nt < 4; ++nt) {
                    size_t addr = ((size_t)b * C_ + oc) * DHW_ + (s0 + nt * 16 + li);
                    float v = acc[mt][nt][r] + bb;
                    if (LEAKY) v = (v >= 0.0f) ? v : 0.1f * v;
                    if (RESID) v += resid[addr];
                    dstf[addr] = v;
                }
            }
        }
    }
}

extern "C" void kernel_launch(void* const* d_in, const int* in_sizes, int n_in,
                              void* d_out, int out_size, void* d_ws, size_t ws_size,
                              hipStream_t stream) {
    const float* x      = (const float*)d_in[0];
    const float* w_off0 = (const float*)d_in[1];
    const float* b_off0 = (const float*)d_in[2];
    const float* w0     = (const float*)d_in[3];
    const float* b0     = (const float*)d_in[4];
    const float* w_off1 = (const float*)d_in[5];
    const float* b_off1 = (const float*)d_in[6];
    const float* w1     = (const float*)d_in[7];
    const float* b1     = (const float*)d_in[8];
    float* out = (float*)d_out;

    // ws: off (54*NLOC f32) | xcl (48*NLOC bf16) | hcl (48*NLOC bf16) | wf_off | wf_conv
    float* off_buf = (float*)d_ws;
    unsigned short* xcl = (unsigned short*)(off_buf + (size_t)OFFC_ * NLOC_);
    unsigned short* hcl = xcl + (size_t)NLOC_ * 48;
    unsigned short* wf_off  = hcl + (size_t)NLOC_ * 48;
    unsigned short* wf_conv = wf_off + 27 * 4 * 1024;

    dim3 blk(256);
    int nblocks = NLOC_ / 256;  // 588

    to_cl_kernel<<<nblocks, blk, 0, stream>>>(x, xcl);

    // --- layer 0 ---
    repack_frag_kernel<<<(27 * 4 * 1024 + 255) / 256, blk, 0, stream>>>(w_off0, wf_off, OFFC_, 4);
    repack_frag_kernel<<<(27 * 3 * 1024 + 255) / 256, blk, 0, stream>>>(w0, wf_conv, C_, 3);
    offconv_mfma<<<nblocks, blk, 0, stream>>>(xcl, wf_off, b_off0, off_buf);
    deform_mfma<1, 0, 1><<<nblocks, blk, 0, stream>>>(xcl, off_buf, wf_conv, b0, nullptr, nullptr, hcl);

    // --- layer 1 ---
    repack_frag_kernel<<<(27 * 4 * 1024 + 255) / 256, blk, 0, stream>>>(w_off1, wf_off, OFFC_, 4);
    repack_frag_kernel<<<(27 * 3 * 1024 + 255) / 256, blk, 0, stream>>>(w1, wf_conv, C_, 3);
    offconv_mfma<<<nblocks, blk, 0, stream>>>(hcl, wf_off, b_off1, off_buf);
    deform_mfma<0, 1, 0><<<nblocks, blk, 0, stream>>>(hcl, off_buf, wf_conv, b1, x, out, nullptr);
}

// Round 8
// 296.768 us; speedup vs baseline: 1.6276x; 1.1930x over previous
//
#include <hip/hip_runtime.h>
#include <hip/hip_bf16.h>

// (B, nf, D, H, W) = (4, 48, 12, 56, 56), fp32 in/out, bf16 MFMA internally.
// Sampled tensors are stored as SIX bf16 chunk-planes [6][NLOC][8ch]: each
// bilinear corner load is a 16B read at 16B pixel stride (~16 line-touches
// per wave-instruction). Round 7/8: taps SPLIT across a wave pair sharing
// the same 64 locations (block=128) -> 2x waves in flight; partial
// accumulators reduced through LDS. Round 8 fix: __syncthreads() BEFORE the
// exchange writes (round 7 raced wave1's XCH writes vs wave0's staging reads).
constexpr int B_ = 4, C_ = 48, D_ = 12, H_ = 56, W_ = 56;
constexpr int DHW_ = D_ * H_ * W_;        // 37632
constexpr int NLOC_ = B_ * DHW_;          // 150528 -> 2352 blocks of 128
constexpr int OFFC_ = 54;                 // 27 taps x 2 (dh, dw)
constexpr int NXCD_ = 8;

typedef short bf16x8 __attribute__((ext_vector_type(8)));
typedef float f32x4  __attribute__((ext_vector_type(4)));
typedef unsigned int u32x4 __attribute__((ext_vector_type(4)));
typedef unsigned int u32x2 __attribute__((ext_vector_type(2)));

__device__ __forceinline__ int xcd_swizzle(int bid, int nwg) {
    int xcd = bid % NXCD_, lid = bid / NXCD_;
    int q = nwg / NXCD_, r = nwg % NXCD_;
    return (xcd < r ? xcd * (q + 1) : r * (q + 1) + (xcd - r) * q) + lid;
}

__device__ __forceinline__ unsigned int f2bf_u(float f) {
    __hip_bfloat16 h = __float2bfloat16(f);
    return (unsigned int)__builtin_bit_cast(unsigned short, h);
}
__device__ __forceinline__ float bflo(unsigned int pv) {
    return __builtin_bit_cast(float, pv << 16);
}
__device__ __forceinline__ float bfhi(unsigned int pv) {
    return __builtin_bit_cast(float, pv & 0xffff0000u);
}

// 4-corner bilinear on a 16B chunk (8 bf16 channels), fp32 math, bf16 out.
__device__ __forceinline__ u32x4 interp4(u32x4 c00, u32x4 c01, u32x4 c10, u32x4 c11,
                                         f32x4 cw) {
    u32x4 pv;
#pragma unroll
    for (int u = 0; u < 4; ++u) {
        float lo = cw[0] * bflo(c00[u]);
        lo = fmaf(cw[1], bflo(c01[u]), lo);
        lo = fmaf(cw[2], bflo(c10[u]), lo);
        lo = fmaf(cw[3], bflo(c11[u]), lo);
        float hi = cw[0] * bfhi(c00[u]);
        hi = fmaf(cw[1], bfhi(c01[u]), hi);
        hi = fmaf(cw[2], bfhi(c10[u]), hi);
        hi = fmaf(cw[3], bfhi(c11[u]), hi);
        pv[u] = f2bf_u(lo) | (f2bf_u(hi) << 16);
    }
    return pv;
}

// Pack weights into MFMA A-fragment order (bf16):
// wf[k][mt][ks][lane][i] = W[oc=mt*16+(lane&15)][c=ks*32+8*(lane>>4)+i][tap k]
__global__ void __launch_bounds__(256) repack_frag_kernel(
    const float* __restrict__ w, unsigned short* __restrict__ wf, int OC, int MT) {
    int t = blockIdx.x * 256 + threadIdx.x;
    int total = 27 * MT * 1024;
    if (t >= total) return;
    int i    = t & 7;
    int lane = (t >> 3) & 63;
    int ks   = (t >> 9) & 1;
    int mt   = (t >> 10) % MT;
    int k    = t / (MT << 10);
    int oc = mt * 16 + (lane & 15);
    int c  = ks * 32 + 8 * (lane >> 4) + i;
    float v = (oc < OC && c < 48) ? w[((size_t)oc * 48 + c) * 27 + k] : 0.0f;
    wf[t] = (unsigned short)f2bf_u(v);
}

// fp32 [B][48][DHW] -> bf16 chunk-planes [6][NLOC][8].
__global__ void __launch_bounds__(256) to_cl_kernel(const float* __restrict__ x,
                                                    unsigned short* __restrict__ xcl) {
    int loc = blockIdx.x * 256 + threadIdx.x;
    int b = loc / DHW_, s = loc - b * DHW_;
    const float* xp = x + (size_t)b * (C_ * DHW_) + s;
#pragma unroll
    for (int q = 0; q < 6; ++q) {
        float v[8];
#pragma unroll
        for (int u = 0; u < 8; ++u) v[u] = xp[(size_t)(q * 8 + u) * DHW_];
        u32x4 o;
#pragma unroll
        for (int u = 0; u < 4; ++u)
            o[u] = f2bf_u(v[2 * u]) | (f2bf_u(v[2 * u + 1]) << 16);
        *(u32x4*)(xcl + ((size_t)q * NLOC_ + loc) * 8) = o;   // 16B/lane dense
    }
}

// ---------------- offset conv (plain 3x3x3, 54 outputs) via MFMA ----------------
// 2 waves share 64 locations; wave w does taps k === w (mod 2).
__global__ void __launch_bounds__(128) offconv_mfma(
    const unsigned short* __restrict__ xcl,   // [6][NLOC][8] bf16 chunk-planes
    const unsigned short* __restrict__ wf,    // frag-packed, MT=4
    const float* __restrict__ bo,             // [54]
    float* __restrict__ off) {                // [B][54][DHW] fp32
    __shared__ unsigned short S[2][64][64];
    int tid = threadIdx.x, wid = tid >> 6, lane = tid & 63;
    int base = xcd_swizzle(blockIdx.x, gridDim.x) * 64;
    int loc = base + lane;
    int b = loc / DHW_;
    int sp = loc - b * DHW_;
    int w = sp % W_; int t1 = sp / W_;
    int h = t1 % H_; int d = t1 / H_;
    int g = lane >> 4, li = lane & 15, l7 = lane & 7;

    u32x4 z = {0, 0, 0, 0};
    *(u32x4*)&S[wid][lane][(6 ^ l7) * 8] = z;   // K-pad channels 48..63
    *(u32x4*)&S[wid][lane][(7 ^ l7) * 8] = z;

    f32x4 acc[4][4];
#pragma unroll
    for (int mt = 0; mt < 4; ++mt)
#pragma unroll
        for (int nt = 0; nt < 4; ++nt) acc[mt][nt] = (f32x4){0.f, 0.f, 0.f, 0.f};

    const u32x4* plane[6];
#pragma unroll
    for (int q = 0; q < 6; ++q)
        plane[q] = (const u32x4*)(xcl + ((size_t)q * NLOC_ + (size_t)b * DHW_) * 8);

#pragma unroll 1
    for (int i = 0; i < 14; ++i) {
        int k = wid + 2 * i;
        if (k >= 27) break;
        int kd = k / 9 - 1, kh = (k / 3) % 3 - 1, kw = k % 3 - 1;
        int pd = d + kd, ph = h + kh, pw = w + kw;
        bool valid = (pd >= 0) & (pd < D_) & (ph >= 0) & (ph < H_) & (pw >= 0) & (pw < W_);
        int pdc = min(max(pd, 0), D_ - 1);
        int phc = min(max(ph, 0), H_ - 1);
        int pwc = min(max(pw, 0), W_ - 1);
        int pix = (pdc * H_ + phc) * W_ + pwc;
        u32x4 pv[6];
#pragma unroll
        for (int cc = 0; cc < 6; ++cc) pv[cc] = plane[cc][pix];   // coalesced 16B
#pragma unroll
        for (int cc = 0; cc < 6; ++cc) {
            if (!valid) pv[cc] = z;
            *(u32x4*)&S[wid][lane][(cc ^ l7) * 8] = pv[cc];
        }
        const unsigned short* wk = wf + (size_t)k * 4096 + lane * 8;
        bf16x8 a[4][2];
#pragma unroll
        for (int mt = 0; mt < 4; ++mt)
#pragma unroll
            for (int ks = 0; ks < 2; ++ks)
                a[mt][ks] = *(const bf16x8*)&wk[(mt * 2 + ks) * 512];
#pragma unroll
        for (int nt = 0; nt < 4; ++nt) {
            const unsigned short* sr = &S[wid][nt * 16 + li][0];
            bf16x8 b0 = *(const bf16x8*)&sr[((0 + g) ^ l7) * 8];
            bf16x8 b1 = *(const bf16x8*)&sr[((4 + g) ^ l7) * 8];
#pragma unroll
            for (int mt = 0; mt < 4; ++mt) {
                acc[mt][nt] = __builtin_amdgcn_mfma_f32_16x16x32_bf16(a[mt][0], b0, acc[mt][nt], 0, 0, 0);
                acc[mt][nt] = __builtin_amdgcn_mfma_f32_16x16x32_bf16(a[mt][1], b1, acc[mt][nt], 0, 0, 0);
            }
        }
    }

    // cross-wave tap reduction through S (two 8KB phases, static indexing).
    // Barrier FIRST: wave 0 must be done reading its staging tile (XCH aliases
    // S[0]) before wave 1 overwrites it — this was round 7's NaN race.
    float* XCH = (float*)&S[0][0][0];
    __syncthreads();
    if (wid == 1) {
#pragma unroll
        for (int mt = 0; mt < 2; ++mt)
#pragma unroll
            for (int nt = 0; nt < 4; ++nt)
                *(f32x4*)(XCH + (mt * 4 + nt) * 256 + lane * 4) = acc[mt][nt];
    }
    __syncthreads();
    if (wid == 0) {
#pragma unroll
        for (int mt = 0; mt < 2; ++mt)
#pragma unroll
            for (int nt = 0; nt < 4; ++nt)
                acc[mt][nt] += *(f32x4*)(XCH + (mt * 4 + nt) * 256 + lane * 4);
    }
    __syncthreads();
    if (wid == 1) {
#pragma unroll
        for (int mt = 2; mt < 4; ++mt)
#pragma unroll
            for (int nt = 0; nt < 4; ++nt)
                *(f32x4*)(XCH + ((mt - 2) * 4 + nt) * 256 + lane * 4) = acc[mt][nt];
    }
    __syncthreads();
    if (wid == 1) return;
#pragma unroll
    for (int mt = 2; mt < 4; ++mt)
#pragma unroll
        for (int nt = 0; nt < 4; ++nt)
            acc[mt][nt] += *(f32x4*)(XCH + ((mt - 2) * 4 + nt) * 256 + lane * 4);

    int s0 = base - b * DHW_;
#pragma unroll
    for (int mt = 0; mt < 4; ++mt) {
#pragma unroll
        for (int r = 0; r < 4; ++r) {
            int oc = mt * 16 + 4 * g + r;
            if (oc < OFFC_) {
                float bb = bo[oc];
#pragma unroll
                for (int nt = 0; nt < 4; ++nt) {
                    size_t addr = ((size_t)b * OFFC_ + oc) * DHW_ + (s0 + nt * 16 + li);
                    off[addr] = acc[mt][nt][r] + bb;
                }
            }
        }
    }
}

// ---------------- deformable conv (bilinear HW, integer D) via MFMA ----------------
template <int LEAKY, int RESID, int CLOUT>
__global__ void __launch_bounds__(128) deform_mfma(
    const unsigned short* __restrict__ scl,   // [6][NLOC][8] bf16 chunk-planes
    const float* __restrict__ off,            // [B][54][DHW] fp32
    const unsigned short* __restrict__ wf,    // frag-packed, MT=3
    const float* __restrict__ bias,           // [48]
    const float* __restrict__ resid,          // [B][48][DHW] fp32 (RESID)
    float* __restrict__ dstf,                 // [B][48][DHW] fp32 (!CLOUT)
    unsigned short* __restrict__ dstcl) {     // [6][NLOC][8] bf16 (CLOUT)
    __shared__ unsigned short S[2][64][64];
    int tid = threadIdx.x, wid = tid >> 6, lane = tid & 63;
    int base = xcd_swizzle(blockIdx.x, gridDim.x) * 64;
    int loc = base + lane;
    int b = loc / DHW_;
    int sp = loc - b * DHW_;
    int w = sp % W_; int t1 = sp / W_;
    int h = t1 % H_; int d = t1 / H_;
    int g = lane >> 4, li = lane & 15, l7 = lane & 7;

    u32x4 z = {0, 0, 0, 0};
    *(u32x4*)&S[wid][lane][(6 ^ l7) * 8] = z;
    *(u32x4*)&S[wid][lane][(7 ^ l7) * 8] = z;

    f32x4 acc[3][4];
#pragma unroll
    for (int mt = 0; mt < 3; ++mt)
#pragma unroll
        for (int nt = 0; nt < 4; ++nt) acc[mt][nt] = (f32x4){0.f, 0.f, 0.f, 0.f};

    const u32x4* plane[6];
#pragma unroll
    for (int q = 0; q < 6; ++q)
        plane[q] = (const u32x4*)(scl + ((size_t)q * NLOC_ + (size_t)b * DHW_) * 8);
    const float* ob = off + (size_t)b * (OFFC_ * DHW_) + sp;

#pragma unroll 1
    for (int i = 0; i < 14; ++i) {
        int k = wid + 2 * i;
        if (k >= 27) break;
        int kd = k / 9 - 1, kh = (k / 3) % 3 - 1, kw = k % 3 - 1;
        int pd = d + kd;
        bool vd = (pd >= 0) & (pd < D_);
        int pdc = min(max(pd, 0), D_ - 1);

        float odh = ob[(size_t)(2 * k + 0) * DHW_];
        float odw = ob[(size_t)(2 * k + 1) * DHW_];
        float phf = (float)(h + kh) + odh;
        float pwf = (float)(w + kw) + odw;
        float h0f = floorf(phf), w0f = floorf(pwf);
        float th = phf - h0f, tw = pwf - w0f;
        int h0 = (int)h0f, w0 = (int)w0f;

        int pix[4];
        f32x4 cw;
#pragma unroll
        for (int dh = 0; dh < 2; ++dh) {
            int hh = h0 + dh;
            bool vh = vd & (hh >= 0) & (hh < H_);
            int hhc = min(max(hh, 0), H_ - 1);
            float wh = dh ? th : 1.0f - th;
#pragma unroll
            for (int dw = 0; dw < 2; ++dw) {
                int ww = w0 + dw;
                bool v = vh & (ww >= 0) & (ww < W_);
                int wwc = min(max(ww, 0), W_ - 1);
                float wwt = dw ? tw : 1.0f - tw;
                pix[dh * 2 + dw] = (pdc * H_ + hhc) * W_ + wwc;   // clamped in-bounds
                cw[dh * 2 + dw] = v ? wh * wwt : 0.0f;
            }
        }

        // two halves of 12 staged 16B gathers (3 chunk-planes x 4 corners)
#pragma unroll
        for (int half = 0; half < 2; ++half) {
            u32x4 st[3][4];
#pragma unroll
            for (int cc = 0; cc < 3; ++cc)
#pragma unroll
                for (int j = 0; j < 4; ++j)
                    st[cc][j] = plane[half * 3 + cc][pix[j]];
#pragma unroll
            for (int cc = 0; cc < 3; ++cc) {
                u32x4 pv = interp4(st[cc][0], st[cc][1], st[cc][2], st[cc][3], cw);
                *(u32x4*)&S[wid][lane][((half * 3 + cc) ^ l7) * 8] = pv;
            }
        }

        const unsigned short* wk = wf + (size_t)k * 3072 + lane * 8;
        bf16x8 a[3][2];
#pragma unroll
        for (int mt = 0; mt < 3; ++mt)
#pragma unroll
            for (int ks = 0; ks < 2; ++ks)
                a[mt][ks] = *(const bf16x8*)&wk[(mt * 2 + ks) * 512];
#pragma unroll
        for (int nt = 0; nt < 4; ++nt) {
            const unsigned short* sr = &S[wid][nt * 16 + li][0];
            bf16x8 b0 = *(const bf16x8*)&sr[((0 + g) ^ l7) * 8];
            bf16x8 b1 = *(const bf16x8*)&sr[((4 + g) ^ l7) * 8];
#pragma unroll
            for (int mt = 0; mt < 3; ++mt) {
                acc[mt][nt] = __builtin_amdgcn_mfma_f32_16x16x32_bf16(a[mt][0], b0, acc[mt][nt], 0, 0, 0);
                acc[mt][nt] = __builtin_amdgcn_mfma_f32_16x16x32_bf16(a[mt][1], b1, acc[mt][nt], 0, 0, 0);
            }
        }
    }

    // cross-wave tap reduction through S[1] (keeps S[0] free for CLOUT
    // transpose). Barrier first: no wave may still be using its staging tile.
    float* XCH = (float*)&S[1][0][0];   // 8KB = 8 groups of 1KB
    __syncthreads();
    if (wid == 1) {
#pragma unroll
        for (int mt = 0; mt < 2; ++mt)
#pragma unroll
            for (int nt = 0; nt < 4; ++nt)
                *(f32x4*)(XCH + (mt * 4 + nt) * 256 + lane * 4) = acc[mt][nt];
    }
    __syncthreads();
    if (wid == 0) {
#pragma unroll
        for (int mt = 0; mt < 2; ++mt)
#pragma unroll
            for (int nt = 0; nt < 4; ++nt)
                acc[mt][nt] += *(f32x4*)(XCH + (mt * 4 + nt) * 256 + lane * 4);
    }
    __syncthreads();
    if (wid == 1) {
#pragma unroll
        for (int nt = 0; nt < 4; ++nt)
            *(f32x4*)(XCH + nt * 256 + lane * 4) = acc[2][nt];
    }
    __syncthreads();
    if (wid == 1) return;
#pragma unroll
    for (int nt = 0; nt < 4; ++nt)
        acc[2][nt] += *(f32x4*)(XCH + nt * 256 + lane * 4);

    if (CLOUT) {
        // Transpose D-tile through wave0's (now free) S[0] tile, then write
        // bf16 chunk-planes: 16B/lane dense per plane, fully coalesced.
        unsigned short* Sb = &S[0][0][0];   // row stride 64 u16 = 128 B
#pragma unroll
        for (int mt = 0; mt < 3; ++mt) {
#pragma unroll
            for (int nt = 0; nt < 4; ++nt) {
                float v[4];
#pragma unroll
                for (int r = 0; r < 4; ++r) {
                    int oc = mt * 16 + 4 * g + r;
                    float t = acc[mt][nt][r] + bias[oc];
                    if (LEAKY) t = (t >= 0.f) ? t : 0.1f * t;
                    v[r] = t;
                }
                int row = nt * 16 + li;
                int colb = (mt * 32 + 8 * g) ^ ((li & 7) << 4);
                u32x2 pp = {f2bf_u(v[0]) | (f2bf_u(v[1]) << 16),
                            f2bf_u(v[2]) | (f2bf_u(v[3]) << 16)};
                *(u32x2*)((char*)(Sb + (size_t)row * 64) + colb) = pp;
            }
        }
        unsigned short* myrow = Sb + (size_t)lane * 64;
#pragma unroll
        for (int s = 0; s < 6; ++s) {
            u32x4 c = *(u32x4*)((char*)myrow + ((s * 16) ^ ((lane & 7) << 4)));
            *(u32x4*)(dstcl + ((size_t)s * NLOC_ + loc) * 8) = c;
        }
    } else {
        int s0 = base - b * DHW_;
#pragma unroll
        for (int mt = 0; mt < 3; ++mt) {
#pragma unroll
            for (int r = 0; r < 4; ++r) {
                int oc = mt * 16 + 4 * g + r;
                float bb = bias[oc];
#pragma unroll
                for (int nt = 0; nt < 4; ++nt) {
                    size_t addr = ((size_t)b * C_ + oc) * DHW_ + (s0 + nt * 16 + li);
                    float v = acc[mt][nt][r] + bb;
                    if (LEAKY) v = (v >= 0.0f) ? v : 0.1f * v;
                    if (RESID) v += resid[addr];
                    dstf[addr] = v;
                }
            }
        }
    }
}

extern "C" void kernel_launch(void* const* d_in, const int* in_sizes, int n_in,
                              void* d_out, int out_size, void* d_ws, size_t ws_size,
                              hipStream_t stream) {
    const float* x      = (const float*)d_in[0];
    const float* w_off0 = (const float*)d_in[1];
    const float* b_off0 = (const float*)d_in[2];
    const float* w0     = (const float*)d_in[3];
    const float* b0     = (const float*)d_in[4];
    const float* w_off1 = (const float*)d_in[5];
    const float* b_off1 = (const float*)d_in[6];
    const float* w1     = (const float*)d_in[7];
    const float* b1     = (const float*)d_in[8];
    float* out = (float*)d_out;

    // ws: off (54*NLOC f32) | xcl (48*NLOC bf16) | hcl (48*NLOC bf16) | wf_off | wf_conv
    float* off_buf = (float*)d_ws;
    unsigned short* xcl = (unsigned short*)(off_buf + (size_t)OFFC_ * NLOC_);
    unsigned short* hcl = xcl + (size_t)NLOC_ * 48;
    unsigned short* wf_off  = hcl + (size_t)NLOC_ * 48;
    unsigned short* wf_conv = wf_off + 27 * 4 * 1024;

    dim3 blk128(128), blk256(256);
    int nblk = NLOC_ / 64;    // 2352 (divisible by 8)

    to_cl_kernel<<<NLOC_ / 256, blk256, 0, stream>>>(x, xcl);

    // --- layer 0 ---
    repack_frag_kernel<<<(27 * 4 * 1024 + 255) / 256, blk256, 0, stream>>>(w_off0, wf_off, OFFC_, 4);
    repack_frag_kernel<<<(27 * 3 * 1024 + 255) / 256, blk256, 0, stream>>>(w0, wf_conv, C_, 3);
    offconv_mfma<<<nblk, blk128, 0, stream>>>(xcl, wf_off, b_off0, off_buf);
    deform_mfma<1, 0, 1><<<nblk, blk128, 0, stream>>>(xcl, off_buf, wf_conv, b0, nullptr, nullptr, hcl);

    // --- layer 1 ---
    repack_frag_kernel<<<(27 * 4 * 1024 + 255) / 256, blk256, 0, stream>>>(w_off1, wf_off, OFFC_, 4);
    repack_frag_kernel<<<(27 * 3 * 1024 + 255) / 256, blk256, 0, stream>>>(w1, wf_conv, C_, 3);
    offconv_mfma<<<nblk, blk128, 0, stream>>>(hcl, wf_off, b_off1, off_buf);
    deform_mfma<0, 1, 0><<<nblk, blk128, 0, stream>>>(hcl, off_buf, wf_conv, b1, x, out, nullptr);
}